// Round 13
// baseline (176.830 us; speedup 1.0000x reference)
//
#include <hip/hip_runtime.h>
#include <hip/hip_bf16.h>

#define NN     500000
#define DIN    256
#define DATT   128
#define NG     4096
#define MT     32
#define NT32   15625      // NN / 32, exact (no partial tiles)
#define NBLOCKS 768       // 3 per CU
#define TPB    21         // ceil(15625/768); 768*21 = 16128

typedef __attribute__((ext_vector_type(8))) short short8;
typedef __attribute__((ext_vector_type(4))) float f32x4;

// pack two f32 -> two bf16 (round-half-up)
__device__ __forceinline__ unsigned int pack2bf(float a, float b) {
    unsigned int ua = __float_as_uint(a) + 0x8000u;
    unsigned int ub = __float_as_uint(b) + 0x8000u;
    return __builtin_amdgcn_perm(ub, ua, 0x07060302);  // [ub.b3,ub.b2,ua.b3,ua.b2]
}

// tanh(x) = 1 - 2/(1+e^{2x})
__device__ __forceinline__ float tanh_fast(float v) {
    float e = __expf(2.f * v);
    return 1.f - 2.f * __builtin_amdgcn_rcpf(e + 1.f);
}

// LDS-only barrier: drains DS ops (writer-side visibility) but leaves global
// loads IN FLIGHT across the barrier (T4: never vmcnt(0) in the main loop).
__device__ __forceinline__ void lds_barrier() {
    asm volatile("s_waitcnt lgkmcnt(0)" ::: "memory");
    __builtin_amdgcn_s_barrier();
    asm volatile("" ::: "memory");
}

// one-time: W1 [256][128] fp32 -> W1t [128][256] bf16 (transposed) in d_ws
__global__ void prep_w1t(const float* __restrict__ W1, unsigned short* __restrict__ W1t) {
    int c = blockIdx.x;      // 0..127
    int k = threadIdx.x;     // 0..255
    unsigned int u = __float_as_uint(W1[k * DATT + c]) + 0x8000u;
    W1t[c * DIN + k] = (unsigned short)(u >> 16);
}

// Multi-tile pipelined fused kernel. 3 blocks/CU, 21 contiguous 32-node tiles
// per block, double-buffered bf16 LDS; t+1 prefetch stays in flight across the
// lds_barriers. Pooling phase is split {branch-free xv[32] LDS preload ->
// branchy register accumulate}: the atomic-flush branches previously exposed
// ~120cy of ds_read latency on EVERY of the 32 iterations (~4.2k cy/tile);
// preloading lets the 32 ds_read_u16 pipeline (~300 cy total).
__global__ __launch_bounds__(256, 3)
void attnpool_kernel(const float* __restrict__ x,
                     const int* __restrict__ batch,
                     const unsigned short* __restrict__ W1t,
                     const float* __restrict__ b1,
                     const float* __restrict__ W2,
                     const float* __restrict__ b2,
                     float* __restrict__ out)
{
    __shared__ unsigned short xb[2][MT * DIN];   // 2 x 16 KB, XOR-swizzled
    __shared__ float part[4][MT];

    const int t0 = blockIdx.x * TPB;
    if (t0 >= NT32) return;
    const int tEnd = (t0 + TPB < NT32) ? t0 + TPB : NT32;

    const int tid = threadIdx.x;
    const int w   = tid >> 6;        // wave 0..3
    const int l   = tid & 63;
    const int lr  = l & 15;
    const int lg  = l >> 4;

    // ---- per-block constants: A-frags (W1^T rows 32w..32w+31), biases
    short8 afr[16];
    {
        const unsigned short* A0 = W1t + (32 * w + lr) * DIN;
        #pragma unroll
        for (int kc = 0; kc < 8; ++kc) {
            afr[kc]     = *reinterpret_cast<const short8*>(A0 + 32 * kc + 8 * lg);
            afr[8 + kc] = *reinterpret_cast<const short8*>(A0 + 16 * DIN + 32 * kc + 8 * lg);
        }
    }
    float4 b1v[2], w2v[2];
    #pragma unroll
    for (int r2 = 0; r2 < 2; ++r2) {
        int c0 = 32 * w + 16 * r2 + 4 * lg;
        b1v[r2] = *reinterpret_cast<const float4*>(&b1[c0]);
        w2v[r2] = *reinterpret_cast<const float4*>(&W2[c0]);
    }
    const float b2s = b2[0];

    // ---- prologue: load tile t0 into prefetch regs (8 float4 = 32 VGPR)
    const float4* xg = (const float4*)x;
    float4 pf[8];
    {
        int base = t0 * (MT * 64);        // float4 index; max 32M < 2^31
        #pragma unroll
        for (int i = 0; i < 8; ++i) pf[i] = xg[base + tid + i * 256];
    }

    float accum = 0.f;
    int gcur = -1;
    int cur = 0;

    for (int t = t0; t < tEnd; ++t) {
        // ---- write pf (tile t) -> xb[cur], bf16 swizzled
        unsigned short* X = xb[cur];
        #pragma unroll
        for (int i = 0; i < 8; ++i) {
            int j = tid + i * 256;        // float4-chunk id 0..2047
            int r = j >> 6, c4 = j & 63;  // row 0..31, float4-in-row
            int byte = r * 512 + ((c4 * 8) ^ ((r & 7) << 4));
            *reinterpret_cast<uint2*>(reinterpret_cast<char*>(X) + byte) =
                make_uint2(pack2bf(pf[i].x, pf[i].y), pack2bf(pf[i].z, pf[i].w));
        }
        // per-wave batch ids for tile t (lanes 0..31 <-> nodes 0..31)
        int bvt = -1;
        if (l < 32) {
            int g = batch[t * MT + l];
            bvt = ((unsigned)g < NG) ? g : -1;
        }
        lds_barrier();                    // X ready; pf regs free; vmcnt NOT drained

        // ---- issue tile t+1 loads now; land before next iteration's pack2bf
        if (t + 1 < tEnd) {
            int base = (t + 1) * (MT * 64);
            #pragma unroll
            for (int i = 0; i < 8; ++i) pf[i] = xg[base + tid + i * 256];
        }

        // ---- GEMM h^T: acc[r2][ct] = h-cols [32w+16r2,+16) x nodes [16ct,+16)
        f32x4 acc[2][2];
        #pragma unroll
        for (int r2 = 0; r2 < 2; ++r2)
            #pragma unroll
            for (int ct = 0; ct < 2; ++ct)
                acc[r2][ct] = (f32x4){0.f, 0.f, 0.f, 0.f};

        #pragma unroll
        for (int kc = 0; kc < 8; ++kc) {
            int ko = 32 * kc + 8 * lg;
            short8 bfr[2];
            #pragma unroll
            for (int ct = 0; ct < 2; ++ct) {
                int row = 16 * ct + lr;
                int byte = row * 512 + ((ko * 2) ^ ((row & 7) << 4));
                bfr[ct] = *reinterpret_cast<const short8*>(reinterpret_cast<const char*>(X) + byte);
            }
            #pragma unroll
            for (int ct = 0; ct < 2; ++ct) {
                acc[0][ct] = __builtin_amdgcn_mfma_f32_16x16x32_bf16(afr[kc],     bfr[ct], acc[0][ct], 0, 0, 0);
                acc[1][ct] = __builtin_amdgcn_mfma_f32_16x16x32_bf16(afr[8 + kc], bfr[ct], acc[1][ct], 0, 0, 0);
            }
        }

        // ---- attn partials: lane holds h[node=16ct+lr][col=32w+16r2+4lg+j]
        #pragma unroll
        for (int ct = 0; ct < 2; ++ct) {
            float p = 0.f;
            #pragma unroll
            for (int r2 = 0; r2 < 2; ++r2) {
                p += tanh_fast(acc[r2][ct][0] + b1v[r2].x) * w2v[r2].x;
                p += tanh_fast(acc[r2][ct][1] + b1v[r2].y) * w2v[r2].y;
                p += tanh_fast(acc[r2][ct][2] + b1v[r2].z) * w2v[r2].z;
                p += tanh_fast(acc[r2][ct][3] + b1v[r2].w) * w2v[r2].w;
            }
            p += __shfl_xor(p, 16, 64);
            p += __shfl_xor(p, 32, 64);
            if (lg == 0) part[w][16 * ct + lr] = p;
        }
        lds_barrier();                    // part ready; vmcnt NOT drained

        // attn of node (l&31), per wave
        const int nd = l & 31;
        float va = b2s + part[0][nd] + part[1][nd] + part[2][nd] + part[3][nd];

        // ---- pooling preload: branch-free, loads pipeline (32 regs)
        float xv[MT];
        #pragma unroll
        for (int n = 0; n < MT; ++n) {
            int byte = n * 512 + ((tid * 2) ^ ((n & 7) << 4));
            xv[n] = __uint_as_float(
                (unsigned int)(*reinterpret_cast<const unsigned short*>(
                    reinterpret_cast<const char*>(X) + byte)) << 16);
        }

        // ---- pooling accumulate: registers only; boundary atomics
        #pragma unroll
        for (int n = 0; n < MT; ++n) {
            int   g = __builtin_amdgcn_readlane(bvt, n);
            float a = __int_as_float(__builtin_amdgcn_readlane(__float_as_int(va), n));
            if (g != gcur) {              // wave-uniform branch
                if (gcur >= 0) atomicAdd(&out[gcur * DIN + tid], accum);
                accum = 0.f;
                gcur = g;
            }
            accum = fmaf(a, xv[n], accum);
        }
        cur ^= 1;
    }
    if (gcur >= 0) atomicAdd(&out[gcur * DIN + tid], accum);
}

extern "C" void kernel_launch(void* const* d_in, const int* in_sizes, int n_in,
                              void* d_out, int out_size, void* d_ws, size_t ws_size,
                              hipStream_t stream) {
    const float* x     = (const float*)d_in[0];
    const int*   batch = (const int*)d_in[1];     // int32 (JAX x64 disabled)
    const float* W1 = (const float*)d_in[3];
    const float* b1 = (const float*)d_in[4];
    const float* W2 = (const float*)d_in[5];
    const float* b2 = (const float*)d_in[6];
    float* out = (float*)d_out;
    unsigned short* W1t = (unsigned short*)d_ws;   // 64 KB

    hipMemsetAsync(out, 0, (size_t)NG * DIN * sizeof(float), stream);
    prep_w1t<<<DATT, DIN, 0, stream>>>(W1, W1t);
    attnpool_kernel<<<NBLOCKS, 256, 0, stream>>>(x, batch, W1t, b1, W2, b2, out);
}

// Round 14
// 136.616 us; speedup vs baseline: 1.2944x; 1.2944x over previous
//
#include <hip/hip_runtime.h>
#include <hip/hip_bf16.h>

#define NN     500000
#define DIN    256
#define DATT   128
#define NG     4096
#define MT     32
#define NT32   15625      // NN / 32, exact (no partial tiles)
#define NBLOCKS 512       // 2 per CU (16 waves/CU at <=128 VGPR)
#define TPB    31         // ceil(15625/512); 512*31 = 15872

typedef __attribute__((ext_vector_type(8))) short short8;
typedef __attribute__((ext_vector_type(4))) float f32x4;

// pack two f32 -> two bf16 (round-half-up)
__device__ __forceinline__ unsigned int pack2bf(float a, float b) {
    unsigned int ua = __float_as_uint(a) + 0x8000u;
    unsigned int ub = __float_as_uint(b) + 0x8000u;
    return __builtin_amdgcn_perm(ub, ua, 0x07060302);  // [ub.b3,ub.b2,ua.b3,ua.b2]
}

// tanh(x) = 1 - 2/(1+e^{2x})
__device__ __forceinline__ float tanh_fast(float v) {
    float e = __expf(2.f * v);
    return 1.f - 2.f * __builtin_amdgcn_rcpf(e + 1.f);
}

// LDS-only barrier: drains DS ops but leaves global loads in flight (T4).
__device__ __forceinline__ void lds_barrier() {
    asm volatile("s_waitcnt lgkmcnt(0)" ::: "memory");
    __builtin_amdgcn_s_barrier();
    asm volatile("" ::: "memory");
}

// one-time: W1 [256][128] fp32 -> W1t [128][256] bf16 (transposed) in d_ws
__global__ void prep_w1t(const float* __restrict__ W1, unsigned short* __restrict__ W1t) {
    int c = blockIdx.x;      // 0..127
    int k = threadIdx.x;     // 0..255
    unsigned int u = __float_as_uint(W1[k * DATT + c]) + 0x8000u;
    W1t[c * DIN + k] = (unsigned short)(u >> 16);
}

// 8-wave (512-thread) pipelined fused kernel, 2 blocks/CU -> 16 waves/CU.
// Each wave owns 16 h-cols (afr 32 VGPR); total ~95 VGPR < 128 cap for
// 4 waves/SIMD. 31 contiguous 32-node tiles per block, double-buffered
// bf16 LDS; t+1 prefetch stays in flight across lds_barriers.
// Pooling: thread-half h pools nodes [16h,16h+16) of dim tid&255; two
// independent carried accumulators (sorted subsequences), boundary atomics.
__global__ __launch_bounds__(512, 4)
void attnpool_kernel(const float* __restrict__ x,
                     const int* __restrict__ batch,
                     const unsigned short* __restrict__ W1t,
                     const float* __restrict__ b1,
                     const float* __restrict__ W2,
                     const float* __restrict__ b2,
                     float* __restrict__ out)
{
    __shared__ unsigned short xb[2][MT * DIN];   // 2 x 16 KB, XOR-swizzled
    __shared__ float part[8][MT];

    const int t0 = blockIdx.x * TPB;
    if (t0 >= NT32) return;
    const int tEnd = (t0 + TPB < NT32) ? t0 + TPB : NT32;

    const int tid = threadIdx.x;     // 0..511
    const int w   = tid >> 6;        // wave 0..7
    const int l   = tid & 63;
    const int lr  = l & 15;
    const int lg  = l >> 4;

    // ---- per-block constants: A-frags (W1^T rows 16w..16w+15), biases
    short8 afr[8];
    {
        const unsigned short* A0 = W1t + (16 * w + lr) * DIN;
        #pragma unroll
        for (int kc = 0; kc < 8; ++kc)
            afr[kc] = *reinterpret_cast<const short8*>(A0 + 32 * kc + 8 * lg);
    }
    float4 b1v, w2v;
    {
        int c0 = 16 * w + 4 * lg;
        b1v = *reinterpret_cast<const float4*>(&b1[c0]);
        w2v = *reinterpret_cast<const float4*>(&W2[c0]);
    }
    const float b2s = b2[0];

    // ---- prologue: load tile t0 into prefetch regs (4 float4 = 16 VGPR)
    const float4* xg = (const float4*)x;
    float4 pf[4];
    {
        int base = t0 * (MT * 64);        // float4 index; max 32M < 2^31
        #pragma unroll
        for (int i = 0; i < 4; ++i) pf[i] = xg[base + tid + i * 512];
    }

    float accum = 0.f;
    int gcur = -1;
    int cur = 0;
    const int half = tid >> 8;            // 0: nodes 0..15, 1: nodes 16..31
    const int d    = tid & 255;           // pooled dim

    for (int t = t0; t < tEnd; ++t) {
        // ---- write pf (tile t) -> xb[cur], bf16 swizzled
        unsigned short* X = xb[cur];
        #pragma unroll
        for (int i = 0; i < 4; ++i) {
            int j = tid + i * 512;        // float4-chunk id 0..2047
            int r = j >> 6, c4 = j & 63;  // row 0..31, float4-in-row
            int byte = r * 512 + ((c4 * 8) ^ ((r & 7) << 4));
            *reinterpret_cast<uint2*>(reinterpret_cast<char*>(X) + byte) =
                make_uint2(pack2bf(pf[i].x, pf[i].y), pack2bf(pf[i].z, pf[i].w));
        }
        // per-wave batch ids for tile t (lanes 0..31 <-> nodes 0..31)
        int bvt = -1;
        if (l < 32) {
            int g = batch[t * MT + l];
            bvt = ((unsigned)g < NG) ? g : -1;
        }
        lds_barrier();                    // X ready; pf regs free; vmcnt NOT drained

        // ---- issue tile t+1 loads; land before next iteration's pack2bf
        if (t + 1 < tEnd) {
            int base = (t + 1) * (MT * 64);
            #pragma unroll
            for (int i = 0; i < 4; ++i) pf[i] = xg[base + tid + i * 512];
        }

        // ---- GEMM h^T: acc[ct] = h-cols [16w,16w+16) x nodes [16ct,16ct+16)
        f32x4 acc[2];
        acc[0] = (f32x4){0.f, 0.f, 0.f, 0.f};
        acc[1] = (f32x4){0.f, 0.f, 0.f, 0.f};

        #pragma unroll
        for (int kc = 0; kc < 8; ++kc) {
            int ko = 32 * kc + 8 * lg;
            short8 bfr[2];
            #pragma unroll
            for (int ct = 0; ct < 2; ++ct) {
                int row = 16 * ct + lr;
                int byte = row * 512 + ((ko * 2) ^ ((row & 7) << 4));
                bfr[ct] = *reinterpret_cast<const short8*>(reinterpret_cast<const char*>(X) + byte);
            }
            acc[0] = __builtin_amdgcn_mfma_f32_16x16x32_bf16(afr[kc], bfr[0], acc[0], 0, 0, 0);
            acc[1] = __builtin_amdgcn_mfma_f32_16x16x32_bf16(afr[kc], bfr[1], acc[1], 0, 0, 0);
        }

        // ---- attn partials: lane holds h[node=16ct+lr][col=16w+4lg+j]
        #pragma unroll
        for (int ct = 0; ct < 2; ++ct) {
            float p = tanh_fast(acc[ct][0] + b1v.x) * w2v.x
                    + tanh_fast(acc[ct][1] + b1v.y) * w2v.y
                    + tanh_fast(acc[ct][2] + b1v.z) * w2v.z
                    + tanh_fast(acc[ct][3] + b1v.w) * w2v.w;
            p += __shfl_xor(p, 16, 64);
            p += __shfl_xor(p, 32, 64);
            if (lg == 0) part[w][16 * ct + lr] = p;
        }
        lds_barrier();                    // part ready; vmcnt NOT drained

        // attn of node (l&31): sum 8 wave partials (broadcast LDS reads)
        const int nd = l & 31;
        float va = b2s + part[0][nd] + part[1][nd] + part[2][nd] + part[3][nd]
                       + part[4][nd] + part[5][nd] + part[6][nd] + part[7][nd];

        // ---- pooling: thread-half h pools nodes [16h,16h+16), dim d;
        // accumulator carried ACROSS tiles (block's node range contiguous)
        #pragma unroll
        for (int n = 0; n < 16; ++n) {
            int node = 16 * half + n;
            int   g = __builtin_amdgcn_readlane(bvt, node);
            float a = __int_as_float(__builtin_amdgcn_readlane(__float_as_int(va), node));
            if (g != gcur) {              // wave-uniform branch
                if (gcur >= 0) atomicAdd(&out[gcur * DIN + d], accum);
                accum = 0.f;
                gcur = g;
            }
            int byte = node * 512 + ((d * 2) ^ ((node & 7) << 4));
            float xv = __uint_as_float(
                (unsigned int)(*reinterpret_cast<const unsigned short*>(
                    reinterpret_cast<const char*>(X) + byte)) << 16);
            accum = fmaf(a, xv, accum);
        }
        cur ^= 1;
    }
    if (gcur >= 0) atomicAdd(&out[gcur * DIN + d], accum);
}

extern "C" void kernel_launch(void* const* d_in, const int* in_sizes, int n_in,
                              void* d_out, int out_size, void* d_ws, size_t ws_size,
                              hipStream_t stream) {
    const float* x     = (const float*)d_in[0];
    const int*   batch = (const int*)d_in[1];     // int32 (JAX x64 disabled)
    const float* W1 = (const float*)d_in[3];
    const float* b1 = (const float*)d_in[4];
    const float* W2 = (const float*)d_in[5];
    const float* b2 = (const float*)d_in[6];
    float* out = (float*)d_out;
    unsigned short* W1t = (unsigned short*)d_ws;   // 64 KB

    hipMemsetAsync(out, 0, (size_t)NG * DIN * sizeof(float), stream);
    prep_w1t<<<DATT, DIN, 0, stream>>>(W1, W1t);
    attnpool_kernel<<<NBLOCKS, 512, 0, stream>>>(x, batch, W1t, b1, W2, b2, out);
}